// Round 8
// baseline (270.699 us; speedup 1.0000x reference)
//
#include <hip/hip_runtime.h>
#include <hip/hip_bf16.h>

// ---------- types / helpers ----------
typedef __attribute__((ext_vector_type(8))) short bf16x8;   // 8 bf16 = 4 VGPRs
typedef __attribute__((ext_vector_type(4))) short bf16x4;
typedef __attribute__((ext_vector_type(4))) float f32x4;

__device__ __forceinline__ short f2bf(float f) {
    unsigned u = __float_as_uint(f);
    u += 0x7fff + ((u >> 16) & 1);          // round-to-nearest-even
    return (short)(u >> 16);
}
__device__ __forceinline__ float bf2f(short s) {
    return __uint_as_float(((unsigned)(unsigned short)s) << 16);
}
__device__ __forceinline__ unsigned pk_bf16(float lo, float hi) {
    __hip_bfloat162 t = __float22bfloat162_rn(make_float2(lo, hi));
    unsigned u;
    __builtin_memcpy(&u, &t, 4);
    return u;
}

#define GLOAD_LDS16(gp, lp)                                                            \
    __builtin_amdgcn_global_load_lds(                                                  \
        (const __attribute__((address_space(1))) unsigned*)(gp),                       \
        (__attribute__((address_space(3))) unsigned*)(lp), 16, 0, 0)

#define QK_SCALE 0.180336879f   // (1/sqrt(64)) * log2(e), folded into q at GEMM1
#define MFMA16(a, b, c) __builtin_amdgcn_mfma_f32_16x16x32_bf16((a), (b), (c), 0, 0, 0)

// ---------- fused prep: enc->bf16, biases->bf16, Wa/Wo -> transposed bf16 ----------
__device__ __forceinline__ void tcvt_tile(const float* __restrict__ W, short* __restrict__ Wt,
                                          int K, int N, int bx, int by, int t,
                                          short (*tile)[72]) {
    const int k0 = by * 64, n0 = bx * 64;
    #pragma unroll
    for (int jj = 0; jj < 4; ++jj) {
        int row = jj * 16 + (t >> 4);
        int col = (t & 15) * 4;
        f32x4 v = *(const f32x4*)&W[(size_t)(k0 + row) * N + n0 + col];
        bf16x4 b = {f2bf(v.x), f2bf(v.y), f2bf(v.z), f2bf(v.w)};
        *(bf16x4*)&tile[row][col] = b;
    }
    __syncthreads();
    const int nr = t >> 2, kc = (t & 3) * 16;
    bf16x8 o0, o1;
    #pragma unroll
    for (int j = 0; j < 8; ++j) { o0[j] = tile[kc + j][nr]; o1[j] = tile[kc + 8 + j][nr]; }
    short* dst = &Wt[(size_t)(n0 + nr) * K + k0 + kc];
    *(bf16x8*)dst = o0;
    *(bf16x8*)(dst + 8) = o1;
}

__global__ __launch_bounds__(256) void prep_kernel(
    const float* __restrict__ enc, const float* __restrict__ Wa,
    const float* __restrict__ ba, const float* __restrict__ Wo,
    const float* __restrict__ bo, short* __restrict__ Abf,
    short* __restrict__ WtA, short* __restrict__ bbA,
    short* __restrict__ WtO, short* __restrict__ bbO)
{
    __shared__ alignas(16) short tile[64][72];
    const int id = blockIdx.x, t = threadIdx.x;
    if (id < 2048) {
        const int i = id * 2048 + t * 8;
        f32x4 a = *(const f32x4*)&enc[i];
        f32x4 b = *(const f32x4*)&enc[i + 4];
        bf16x8 o = {f2bf(a.x), f2bf(a.y), f2bf(a.z), f2bf(a.w),
                    f2bf(b.x), f2bf(b.y), f2bf(b.z), f2bf(b.w)};
        *(bf16x8*)&Abf[i] = o;
    } else if (id == 2048) {
        for (int j = t * 8; j < 3072; j += 2048) {
            f32x4 a = *(const f32x4*)&ba[j];
            f32x4 b = *(const f32x4*)&ba[j + 4];
            bf16x8 o = {f2bf(a.x), f2bf(a.y), f2bf(a.z), f2bf(a.w),
                        f2bf(b.x), f2bf(b.y), f2bf(b.z), f2bf(b.w)};
            *(bf16x8*)&bbA[j] = o;
        }
    } else if (id == 2049) {
        if (t < 128) {
            const int j = t * 8;
            f32x4 a = *(const f32x4*)&bo[j];
            f32x4 b = *(const f32x4*)&bo[j + 4];
            bf16x8 o = {f2bf(a.x), f2bf(a.y), f2bf(a.z), f2bf(a.w),
                        f2bf(b.x), f2bf(b.y), f2bf(b.z), f2bf(b.w)};
            *(bf16x8*)&bbO[j] = o;
        }
        __syncthreads();
    } else if (id < 2818) {
        const int lid = id - 2050;
        tcvt_tile(Wa, WtA, 1024, 3072, lid % 48, lid / 48, t, tile);
    } else {
        const int lid = id - 2818;
        tcvt_tile(Wo, WtO, 1024, 1024, lid % 16, lid / 16, t, tile);
    }
}

// ---------- bf16 V slab -> per-head transposed Vt[bh][d][seq] ----------
__global__ __launch_bounds__(256) void vtrans_kernel(const short* __restrict__ qkv,
                                                     short* __restrict__ Vt) {
    __shared__ alignas(16) short T[64][72];
    const int t = threadIdx.x;
    const int seq0 = blockIdx.x * 64;
    const int bh = blockIdx.y, batch = bh >> 4, head = bh & 15;
    #pragma unroll
    for (int jj = 0; jj < 2; ++jj) {
        const int seqr = jj * 32 + (t >> 3);
        const int dcol = (t & 7) * 8;
        bf16x8 v = *(const bf16x8*)&qkv[(size_t)(batch * 2048 + seq0 + seqr) * 3072
                                        + 2048 + head * 64 + dcol];
        #pragma unroll
        for (int j = 0; j < 8; ++j) T[dcol + j][seqr] = v[j];
    }
    __syncthreads();
    #pragma unroll
    for (int jj = 0; jj < 2; ++jj) {
        const int d = jj * 32 + (t >> 3);
        const int sp = (t & 7) * 8;
        bf16x8 v = *(const bf16x8*)&T[d][sp];
        *(bf16x8*)&Vt[((size_t)(batch * 16 + head) * 64 + d) * 2048 + seq0 + sp] = v;
    }
}

// ---------- m97-style BT GEMM: C[M,N] = A[M,K] @ Bt[N,K]^T + bias ----------
template<int BN, bool F32OUT, bool QSCALE>
__global__ __launch_bounds__(256) void gemm_bt(
    const short* __restrict__ A, const short* __restrict__ Bt,
    const short* __restrict__ bias, void* __restrict__ C, int M, int N, int K)
{
    __shared__ alignas(16) short As[128 * 32];
    __shared__ alignas(16) short Bs[BN * 32];

    const int tid = threadIdx.x, w = tid >> 6, lane = tid & 63;
    const int quad = lane >> 4, l16 = lane & 15;
    constexpr int MT = (BN == 128) ? 4 : 2;
    const int wm = (BN == 128) ? (w >> 1) : w;
    const int wn = (BN == 128) ? (w & 1) : 0;
    const int m0 = blockIdx.y * 128, n0 = blockIdx.x * BN;
    const int srow = lane >> 2, scol = (lane & 3) * 8;

    f32x4 acc[MT][4] = {};

    for (int k0 = 0; k0 < K; k0 += 32) {
        __syncthreads();
        #pragma unroll
        for (int jj = 0; jj < 2; ++jj) {
            const int rb = w * 32 + jj * 16;
            GLOAD_LDS16(&A[(size_t)(m0 + rb + srow) * K + k0 + scol], &As[rb * 32]);
        }
        if (BN == 128) {
            #pragma unroll
            for (int jj = 0; jj < 2; ++jj) {
                const int rb = w * 32 + jj * 16;
                GLOAD_LDS16(&Bt[(size_t)(n0 + rb + srow) * K + k0 + scol], &Bs[rb * 32]);
            }
        } else {
            const int rb = w * 16;
            GLOAD_LDS16(&Bt[(size_t)(n0 + rb + srow) * K + k0 + scol], &Bs[rb * 32]);
        }
        __syncthreads();
        bf16x8 af[MT], bfr[4];
        #pragma unroll
        for (int i = 0; i < MT; ++i)
            af[i] = *(const bf16x8*)&As[(wm * (MT * 16) + i * 16 + l16) * 32 + quad * 8];
        #pragma unroll
        for (int i = 0; i < 4; ++i)
            bfr[i] = *(const bf16x8*)&Bs[(wn * 64 + i * 16 + l16) * 32 + quad * 8];
        #pragma unroll
        for (int mt = 0; mt < MT; ++mt)
            #pragma unroll
            for (int nt = 0; nt < 4; ++nt)
                acc[mt][nt] = MFMA16(af[mt], bfr[nt], acc[mt][nt]);
    }

    #pragma unroll
    for (int nt = 0; nt < 4; ++nt) {
        const int col = n0 + wn * 64 + nt * 16 + l16;
        const float bv = bf2f(bias[col]);
        const bool qs = QSCALE && (col < 1024);
        #pragma unroll
        for (int mt = 0; mt < MT; ++mt) {
            const int row = m0 + wm * (MT * 16) + mt * 16 + quad * 4;
            #pragma unroll
            for (int r = 0; r < 4; ++r) {
                float v = acc[mt][nt][r] + bv;
                if (qs) v *= QK_SCALE;
                if (F32OUT) ((float*)C)[(size_t)(row + r) * N + col] = v;
                else        ((short*)C)[(size_t)(row + r) * N + col] = f2bf(v);
            }
        }
    }
}

// ---------- key-split causal flash attention ----------
// 16-row q-tiles, pairs {j, 127-j} -> exactly 33 64-key steps per pair.
// Block = 256 thr / 4 waves; wave chunks {9,8,8,8} of the 33 steps (key-split:
// static-max softmax makes partial (O,l) additive). 2048 blocks x 4 waves =
// 8192 waves (~16-20/CU). Block-end: 3-barrier LDS reduction tree; wave 0
// finalizes both tiles. S^T formulation (K.Q^T) as round 6/7.
__global__ __launch_bounds__(256) void attn_kernel(
    const short* __restrict__ qkv, const short* __restrict__ Vt, short* __restrict__ comb)
{
    __shared__ alignas(16) short Ps[4][16 * 72];        // per-wave P^T buffers
    __shared__ alignas(16) float Cb[2][2][1088];        // [src][tile][64d*16q | 64 l]

    const int tid = threadIdx.x, w = tid >> 6, lane = tid & 63;
    const int quad = lane >> 4, l16 = lane & 15;
    const int bh = blockIdx.x, j = blockIdx.y;
    const int batch = bh >> 4, head = bh & 15;
    const size_t rowbase = (size_t)batch * 2048;
    const int hcol = head * 64;

    const int kA = (j >> 2) + 1;                 // key-tiles for tile A
    const int kB = ((127 - j) >> 2) + 1;         // tile B (kA + kB = 33)
    const int q0A = j * 16, q0B = (127 - j) * 16;
    const short* Vbh = Vt + (size_t)bh * 131072;

    // precomputed per-lane load offsets (shorts)
    int koff[4], voff[4];
    #pragma unroll
    for (int s = 0; s < 4; ++s) koff[s] = (s * 16 + l16) * 3072 + quad * 8;
    #pragma unroll
    for (int dt = 0; dt < 4; ++dt) voff[dt] = (dt * 16 + l16) * 2048 + quad * 8;

    // Q fragments (B-operand: q = l16, d = quad*8+jj (+32))
    bf16x8 qfA[2], qfB[2];
    {
        const short* pa = &qkv[(rowbase + q0A + l16) * 3072 + hcol];
        const short* pb = &qkv[(rowbase + q0B + l16) * 3072 + hcol];
        qfA[0] = *(const bf16x8*)(pa + quad * 8);
        qfA[1] = *(const bf16x8*)(pa + 32 + quad * 8);
        qfB[0] = *(const bf16x8*)(pb + quad * 8);
        qfB[1] = *(const bf16x8*)(pb + 32 + quad * 8);
    }

    f32x4 otA[4] = {}, otB[4] = {};
    float laccA = 0.f, laccB = 0.f;
    short* pw = &Ps[w][0];

    auto do_step = [&](int kc, int q0, bool diag, bf16x8 (&qf)[2],
                       f32x4 (&ot)[4], float& lacc) {
        const short* kb = &qkv[(rowbase + kc * 64) * 3072 + 1024 + hcol];
        const short* vb = Vbh + kc * 64;
        // K fragments (A-operand) — 8 loads off precomputed offsets
        bf16x8 kf[4][2];
        #pragma unroll
        for (int s = 0; s < 4; ++s) {
            kf[s][0] = *(const bf16x8*)&kb[koff[s]];
            kf[s][1] = *(const bf16x8*)&kb[koff[s] + 32];
        }
        f32x4 sv[4];
        #pragma unroll
        for (int s = 0; s < 4; ++s) {
            f32x4 a = {0.f, 0.f, 0.f, 0.f};
            a = MFMA16(kf[s][0], qf[0], a);
            a = MFMA16(kf[s][1], qf[1], a);
            sv[s] = a;
        }
        // V^T fragments issued now; latency hides under softmax
        bf16x8 vf[2][4];
        #pragma unroll
        for (int h = 0; h < 2; ++h)
            #pragma unroll
            for (int dt = 0; dt < 4; ++dt)
                vf[h][dt] = *(const bf16x8*)&vb[voff[dt] + h * 32];

        if (diag) {
            const int qq = q0 + l16;
            #pragma unroll
            for (int s = 0; s < 4; ++s) {
                const int keyb = kc * 64 + s * 16 + quad * 4;
                #pragma unroll
                for (int r = 0; r < 4; ++r)
                    sv[s][r] = (keyb + r <= qq) ? sv[s][r] : -1e30f;
            }
        }
        #pragma unroll
        for (int s = 0; s < 4; ++s) {
            #pragma unroll
            for (int r = 0; r < 4; ++r) sv[s][r] = exp2f(sv[s][r]);
            lacc += (sv[s][0] + sv[s][1]) + (sv[s][2] + sv[s][3]);
            *(unsigned*)&pw[l16 * 72 + s * 16 + quad * 4]     = pk_bf16(sv[s][0], sv[s][1]);
            *(unsigned*)&pw[l16 * 72 + s * 16 + quad * 4 + 2] = pk_bf16(sv[s][2], sv[s][3]);
        }
        asm volatile("" ::: "memory");
        bf16x8 pf0 = *(const bf16x8*)&pw[l16 * 72 + quad * 8];
        bf16x8 pf1 = *(const bf16x8*)&pw[l16 * 72 + 32 + quad * 8];
        asm volatile("" ::: "memory");
        #pragma unroll
        for (int dt = 0; dt < 4; ++dt) {
            ot[dt] = MFMA16(vf[0][dt], pf0, ot[dt]);
            ot[dt] = MFMA16(vf[1][dt], pf1, ot[dt]);
        }
    };

    // wave step chunks: {0..8}, {9..16}, {17..24}, {25..32}
    const int stBeg = (w == 0) ? 0 : 8 * w + 1;
    const int stEnd = 8 * w + 9;
    for (int st = stBeg; st < stEnd; ++st) {
        if (st < kA) do_step(st, q0A, st == kA - 1, qfA, otA, laccA);
        else         do_step(st - kA, q0B, st - kA == kB - 1, qfB, otB, laccB);
    }

    // ---- combine partials across the 4 waves (3-barrier tree) ----
    // O slot: (dt*16+quad*4+r)*16 + l16 ; l slot: 1024 + quad*16 + l16
    const int lslot = 1024 + quad * 16 + l16;
    if (w & 1) {                      // waves 1,3 -> src (w>>1)
        float* c0 = &Cb[w >> 1][0][0];
        float* c1 = &Cb[w >> 1][1][0];
        #pragma unroll
        for (int dt = 0; dt < 4; ++dt)
            #pragma unroll
            for (int r = 0; r < 4; ++r) {
                c0[(dt * 16 + quad * 4 + r) * 16 + l16] = otA[dt][r];
                c1[(dt * 16 + quad * 4 + r) * 16 + l16] = otB[dt][r];
            }
        c0[lslot] = laccA;
        c1[lslot] = laccB;
    }
    __syncthreads();
    if (!(w & 1)) {                   // waves 0,2 add src (w>>1)
        const float* c0 = &Cb[w >> 1][0][0];
        const float* c1 = &Cb[w >> 1][1][0];
        #pragma unroll
        for (int dt = 0; dt < 4; ++dt)
            #pragma unroll
            for (int r = 0; r < 4; ++r) {
                otA[dt][r] += c0[(dt * 16 + quad * 4 + r) * 16 + l16];
                otB[dt][r] += c1[(dt * 16 + quad * 4 + r) * 16 + l16];
            }
        laccA += c0[lslot];
        laccB += c1[lslot];
    }
    __syncthreads();
    if (w == 2) {                     // wave 2 -> src 0
        float* c0 = &Cb[0][0][0];
        float* c1 = &Cb[0][1][0];
        #pragma unroll
        for (int dt = 0; dt < 4; ++dt)
            #pragma unroll
            for (int r = 0; r < 4; ++r) {
                c0[(dt * 16 + quad * 4 + r) * 16 + l16] = otA[dt][r];
                c1[(dt * 16 + quad * 4 + r) * 16 + l16] = otB[dt][r];
            }
        c0[lslot] = laccA;
        c1[lslot] = laccB;
    }
    __syncthreads();
    if (w == 0) {
        const float* c0 = &Cb[0][0][0];
        const float* c1 = &Cb[0][1][0];
        #pragma unroll
        for (int dt = 0; dt < 4; ++dt)
            #pragma unroll
            for (int r = 0; r < 4; ++r) {
                otA[dt][r] += c0[(dt * 16 + quad * 4 + r) * 16 + l16];
                otB[dt][r] += c1[(dt * 16 + quad * 4 + r) * 16 + l16];
            }
        laccA += c0[lslot];
        laccB += c1[lslot];
        // reduce l across quads (lanes sharing l16)
        laccA += __shfl_xor(laccA, 16);
        laccA += __shfl_xor(laccA, 32);
        laccB += __shfl_xor(laccB, 16);
        laccB += __shfl_xor(laccB, 32);
        const float invA = 1.0f / laccA, invB = 1.0f / laccB;
        // tile A: normalize -> Ps[0] -> transpose-store
        #pragma unroll
        for (int dt = 0; dt < 4; ++dt) {
            *(unsigned*)&pw[l16 * 72 + dt * 16 + quad * 4]     = pk_bf16(otA[dt][0] * invA, otA[dt][1] * invA);
            *(unsigned*)&pw[l16 * 72 + dt * 16 + quad * 4 + 2] = pk_bf16(otA[dt][2] * invA, otA[dt][3] * invA);
        }
        asm volatile("" ::: "memory");
        {
            const int qr = lane >> 2, dc = (lane & 3) * 16;
            bf16x8 v0 = *(const bf16x8*)&pw[qr * 72 + dc];
            bf16x8 v1 = *(const bf16x8*)&pw[qr * 72 + dc + 8];
            short* dst = &comb[(rowbase + q0A + qr) * 1024 + hcol + dc];
            *(bf16x8*)dst = v0;
            *(bf16x8*)(dst + 8) = v1;
        }
        asm volatile("" ::: "memory");
        // tile B
        #pragma unroll
        for (int dt = 0; dt < 4; ++dt) {
            *(unsigned*)&pw[l16 * 72 + dt * 16 + quad * 4]     = pk_bf16(otB[dt][0] * invB, otB[dt][1] * invB);
            *(unsigned*)&pw[l16 * 72 + dt * 16 + quad * 4 + 2] = pk_bf16(otB[dt][2] * invB, otB[dt][3] * invB);
        }
        asm volatile("" ::: "memory");
        {
            const int qr = lane >> 2, dc = (lane & 3) * 16;
            bf16x8 v0 = *(const bf16x8*)&pw[qr * 72 + dc];
            bf16x8 v1 = *(const bf16x8*)&pw[qr * 72 + dc + 8];
            short* dst = &comb[(rowbase + q0B + qr) * 1024 + hcol + dc];
            *(bf16x8*)dst = v0;
            *(bf16x8*)(dst + 8) = v1;
        }
    }
}

// ---------- launch ----------
extern "C" void kernel_launch(void* const* d_in, const int* in_sizes, int n_in,
                              void* d_out, int out_size, void* d_ws, size_t ws_size,
                              hipStream_t stream)
{
    const float* enc = (const float*)d_in[0];
    const float* Wa  = (const float*)d_in[1];
    const float* ba  = (const float*)d_in[2];
    const float* Wo  = (const float*)d_in[3];
    const float* bo  = (const float*)d_in[4];
    float* out = (float*)d_out;

    char* ws = (char*)d_ws;
    short* Abf  = (short*)ws;                            // 8 MB; reused as comb
    short* comb = Abf;
    short* WtO  = (short*)(ws + ((size_t)8 << 20));      // 2 MB
    short* bbA  = (short*)(ws + ((size_t)10 << 20));     // 6 KB
    short* bbO  = (short*)(ws + ((size_t)10 << 20) + 16384);
    short* WtA  = (short*)(ws + ((size_t)11 << 20));     // 6 MB (dead after gemm1)
    short* Vtw  = (short*)(ws + ((size_t)11 << 20));     // 8 MB (overlaps dead WtA)
    short* qkv  = (short*)(ws + ((size_t)19 << 20));     // 24 MB

    prep_kernel<<<3074, 256, 0, stream>>>(enc, Wa, ba, Wo, bo, Abf, WtA, bbA, WtO, bbO);
    gemm_bt<128, false, true><<<dim3(24, 32), 256, 0, stream>>>(
        Abf, WtA, bbA, qkv, 4096, 3072, 1024);
    vtrans_kernel<<<dim3(32, 32), 256, 0, stream>>>(qkv, Vtw);
    attn_kernel<<<dim3(32, 64), 256, 0, stream>>>(qkv, Vtw, comb);
    gemm_bt<64, true, false><<<dim3(16, 32), 256, 0, stream>>>(
        comb, WtO, bbO, out, 4096, 1024, 1024);
}

// Round 9
// 246.222 us; speedup vs baseline: 1.0994x; 1.0994x over previous
//
#include <hip/hip_runtime.h>
#include <hip/hip_bf16.h>

// ---------- types / helpers ----------
typedef __attribute__((ext_vector_type(8))) short bf16x8;   // 8 bf16 = 4 VGPRs
typedef __attribute__((ext_vector_type(4))) short bf16x4;
typedef __attribute__((ext_vector_type(4))) float f32x4;

__device__ __forceinline__ short f2bf(float f) {
    unsigned u = __float_as_uint(f);
    u += 0x7fff + ((u >> 16) & 1);          // round-to-nearest-even
    return (short)(u >> 16);
}
__device__ __forceinline__ float bf2f(short s) {
    return __uint_as_float(((unsigned)(unsigned short)s) << 16);
}
__device__ __forceinline__ unsigned pk_bf16(float lo, float hi) {
    __hip_bfloat162 t = __float22bfloat162_rn(make_float2(lo, hi));
    unsigned u;
    __builtin_memcpy(&u, &t, 4);
    return u;
}

#define GLOAD_LDS16(gp, lp)                                                            \
    __builtin_amdgcn_global_load_lds(                                                  \
        (const __attribute__((address_space(1))) unsigned*)(gp),                       \
        (__attribute__((address_space(3))) unsigned*)(lp), 16, 0, 0)

#define QK_SCALE 0.180336879f   // (1/sqrt(64)) * log2(e), folded into q at GEMM1
#define MFMA16(a, b, c) __builtin_amdgcn_mfma_f32_16x16x32_bf16((a), (b), (c), 0, 0, 0)

// ---------- fused prep: enc->bf16, biases->bf16, Wa/Wo -> transposed bf16 ----------
__device__ __forceinline__ void tcvt_tile(const float* __restrict__ W, short* __restrict__ Wt,
                                          int K, int N, int bx, int by, int t,
                                          short (*tile)[72]) {
    const int k0 = by * 64, n0 = bx * 64;
    #pragma unroll
    for (int jj = 0; jj < 4; ++jj) {
        int row = jj * 16 + (t >> 4);
        int col = (t & 15) * 4;
        f32x4 v = *(const f32x4*)&W[(size_t)(k0 + row) * N + n0 + col];
        bf16x4 b = {f2bf(v.x), f2bf(v.y), f2bf(v.z), f2bf(v.w)};
        *(bf16x4*)&tile[row][col] = b;
    }
    __syncthreads();
    const int nr = t >> 2, kc = (t & 3) * 16;
    bf16x8 o0, o1;
    #pragma unroll
    for (int j = 0; j < 8; ++j) { o0[j] = tile[kc + j][nr]; o1[j] = tile[kc + 8 + j][nr]; }
    short* dst = &Wt[(size_t)(n0 + nr) * K + k0 + kc];
    *(bf16x8*)dst = o0;
    *(bf16x8*)(dst + 8) = o1;
}

__global__ __launch_bounds__(256) void prep_kernel(
    const float* __restrict__ enc, const float* __restrict__ Wa,
    const float* __restrict__ ba, const float* __restrict__ Wo,
    const float* __restrict__ bo, short* __restrict__ Abf,
    short* __restrict__ WtA, short* __restrict__ bbA,
    short* __restrict__ WtO, short* __restrict__ bbO)
{
    __shared__ alignas(16) short tile[64][72];
    const int id = blockIdx.x, t = threadIdx.x;
    if (id < 2048) {
        const int i = id * 2048 + t * 8;
        f32x4 a = *(const f32x4*)&enc[i];
        f32x4 b = *(const f32x4*)&enc[i + 4];
        bf16x8 o = {f2bf(a.x), f2bf(a.y), f2bf(a.z), f2bf(a.w),
                    f2bf(b.x), f2bf(b.y), f2bf(b.z), f2bf(b.w)};
        *(bf16x8*)&Abf[i] = o;
    } else if (id == 2048) {
        for (int j = t * 8; j < 3072; j += 2048) {
            f32x4 a = *(const f32x4*)&ba[j];
            f32x4 b = *(const f32x4*)&ba[j + 4];
            bf16x8 o = {f2bf(a.x), f2bf(a.y), f2bf(a.z), f2bf(a.w),
                        f2bf(b.x), f2bf(b.y), f2bf(b.z), f2bf(b.w)};
            *(bf16x8*)&bbA[j] = o;
        }
    } else if (id == 2049) {
        if (t < 128) {
            const int j = t * 8;
            f32x4 a = *(const f32x4*)&bo[j];
            f32x4 b = *(const f32x4*)&bo[j + 4];
            bf16x8 o = {f2bf(a.x), f2bf(a.y), f2bf(a.z), f2bf(a.w),
                        f2bf(b.x), f2bf(b.y), f2bf(b.z), f2bf(b.w)};
            *(bf16x8*)&bbO[j] = o;
        }
        __syncthreads();
    } else if (id < 2818) {
        const int lid = id - 2050;
        tcvt_tile(Wa, WtA, 1024, 3072, lid % 48, lid / 48, t, tile);
    } else {
        const int lid = id - 2818;
        tcvt_tile(Wo, WtO, 1024, 1024, lid % 16, lid / 16, t, tile);
    }
}

// ---------- bf16 V slab -> per-head transposed Vt[bh][d][seq] ----------
__global__ __launch_bounds__(256) void vtrans_kernel(const short* __restrict__ qkv,
                                                     short* __restrict__ Vt) {
    __shared__ alignas(16) short T[64][72];
    const int t = threadIdx.x;
    const int seq0 = blockIdx.x * 64;
    const int bh = blockIdx.y, batch = bh >> 4, head = bh & 15;
    #pragma unroll
    for (int jj = 0; jj < 2; ++jj) {
        const int seqr = jj * 32 + (t >> 3);
        const int dcol = (t & 7) * 8;
        bf16x8 v = *(const bf16x8*)&qkv[(size_t)(batch * 2048 + seq0 + seqr) * 3072
                                        + 2048 + head * 64 + dcol];
        #pragma unroll
        for (int j = 0; j < 8; ++j) T[dcol + j][seqr] = v[j];
    }
    __syncthreads();
    #pragma unroll
    for (int jj = 0; jj < 2; ++jj) {
        const int d = jj * 32 + (t >> 3);
        const int sp = (t & 7) * 8;
        bf16x8 v = *(const bf16x8*)&T[d][sp];
        *(bf16x8*)&Vt[((size_t)(batch * 16 + head) * 64 + d) * 2048 + seq0 + sp] = v;
    }
}

// ---------- m97-style BT GEMM: C[M,N] = A[M,K] @ Bt[N,K]^T + bias ----------
template<int BN, bool F32OUT, bool QSCALE>
__global__ __launch_bounds__(256) void gemm_bt(
    const short* __restrict__ A, const short* __restrict__ Bt,
    const short* __restrict__ bias, void* __restrict__ C, int M, int N, int K)
{
    __shared__ alignas(16) short As[128 * 32];
    __shared__ alignas(16) short Bs[BN * 32];

    const int tid = threadIdx.x, w = tid >> 6, lane = tid & 63;
    const int quad = lane >> 4, l16 = lane & 15;
    constexpr int MT = (BN == 128) ? 4 : 2;
    const int wm = (BN == 128) ? (w >> 1) : w;
    const int wn = (BN == 128) ? (w & 1) : 0;
    const int m0 = blockIdx.y * 128, n0 = blockIdx.x * BN;
    const int srow = lane >> 2, scol = (lane & 3) * 8;

    f32x4 acc[MT][4] = {};

    for (int k0 = 0; k0 < K; k0 += 32) {
        __syncthreads();
        #pragma unroll
        for (int jj = 0; jj < 2; ++jj) {
            const int rb = w * 32 + jj * 16;
            GLOAD_LDS16(&A[(size_t)(m0 + rb + srow) * K + k0 + scol], &As[rb * 32]);
        }
        if (BN == 128) {
            #pragma unroll
            for (int jj = 0; jj < 2; ++jj) {
                const int rb = w * 32 + jj * 16;
                GLOAD_LDS16(&Bt[(size_t)(n0 + rb + srow) * K + k0 + scol], &Bs[rb * 32]);
            }
        } else {
            const int rb = w * 16;
            GLOAD_LDS16(&Bt[(size_t)(n0 + rb + srow) * K + k0 + scol], &Bs[rb * 32]);
        }
        __syncthreads();
        bf16x8 af[MT], bfr[4];
        #pragma unroll
        for (int i = 0; i < MT; ++i)
            af[i] = *(const bf16x8*)&As[(wm * (MT * 16) + i * 16 + l16) * 32 + quad * 8];
        #pragma unroll
        for (int i = 0; i < 4; ++i)
            bfr[i] = *(const bf16x8*)&Bs[(wn * 64 + i * 16 + l16) * 32 + quad * 8];
        #pragma unroll
        for (int mt = 0; mt < MT; ++mt)
            #pragma unroll
            for (int nt = 0; nt < 4; ++nt)
                acc[mt][nt] = MFMA16(af[mt], bfr[nt], acc[mt][nt]);
    }

    #pragma unroll
    for (int nt = 0; nt < 4; ++nt) {
        const int col = n0 + wn * 64 + nt * 16 + l16;
        const float bv = bf2f(bias[col]);
        const bool qs = QSCALE && (col < 1024);
        #pragma unroll
        for (int mt = 0; mt < MT; ++mt) {
            const int row = m0 + wm * (MT * 16) + mt * 16 + quad * 4;
            #pragma unroll
            for (int r = 0; r < 4; ++r) {
                float v = acc[mt][nt][r] + bv;
                if (qs) v *= QK_SCALE;
                if (F32OUT) ((float*)C)[(size_t)(row + r) * N + col] = v;
                else        ((short*)C)[(size_t)(row + r) * N + col] = f2bf(v);
            }
        }
    }
}

// ---------- barrier-free causal flash attention: paired tiles + K pipeline ----------
// Round-7 geometry (best measured): 128-thr blocks, pair {tA, 63-tA} of 32-row
// q-tiles, wave handles 16 rows of each, K/V loads shared by both tiles ->
// uniform 33 steps/wave, 1024 blocks. New: (1) no asm memory fences (they
// pinned load latency to the critical path); (2) next step's K fragments are
// loaded into the same regs right after QK consumes them (software pipeline);
// (3) V issued at step top, used ~500cyc later; (4) per-lane offsets hoisted.
__global__ __launch_bounds__(128) void attn_kernel(
    const short* __restrict__ qkv, const short* __restrict__ Vt, short* __restrict__ comb)
{
    __shared__ alignas(16) short Ps[2][2][16 * 72];   // [wave][tile A/B]

    const int tid = threadIdx.x, w = tid >> 6, lane = tid & 63;
    const int quad = lane >> 4, l16 = lane & 15;
    const int bh = blockIdx.x;
    const int tA = blockIdx.y, tB = 63 - tA;
    const int batch = bh >> 4, head = bh & 15;
    const size_t rowbase = (size_t)batch * 2048;
    const int hcol = head * 64;
    const int q0A = tA * 32 + w * 16, q0B = tB * 32 + w * 16;
    const int diagA = tA >> 1, diagB = tB >> 1;
    const short* Vbh = Vt + (size_t)bh * 131072;
    const short* Kbh = &qkv[rowbase * 3072 + 1024 + hcol];
    short* pwA = &Ps[w][0][0];
    short* pwB = &Ps[w][1][0];

    // per-lane load offsets (in shorts), computed once
    int koff[4], voff[4];
    #pragma unroll
    for (int s = 0; s < 4; ++s) koff[s] = (s * 16 + l16) * 3072 + quad * 8;
    #pragma unroll
    for (int dt = 0; dt < 4; ++dt) voff[dt] = (dt * 16 + l16) * 2048 + quad * 8;

    // Q fragments (B-operand: q = l16, d = quad*8+j (+32))
    bf16x8 qfA[2], qfB[2];
    {
        const short* pa = &qkv[(rowbase + q0A + l16) * 3072 + hcol];
        const short* pb = &qkv[(rowbase + q0B + l16) * 3072 + hcol];
        qfA[0] = *(const bf16x8*)(pa + quad * 8);
        qfA[1] = *(const bf16x8*)(pa + 32 + quad * 8);
        qfB[0] = *(const bf16x8*)(pb + quad * 8);
        qfB[1] = *(const bf16x8*)(pb + 32 + quad * 8);
    }

    f32x4 otA[4] = {}, otB[4] = {};
    float laccA = 0.f, laccB = 0.f;

    // preload K for step 0
    bf16x8 kf[4][2];
    #pragma unroll
    for (int s = 0; s < 4; ++s) {
        kf[s][0] = *(const bf16x8*)&Kbh[koff[s]];
        kf[s][1] = *(const bf16x8*)&Kbh[koff[s] + 32];
    }

    for (int kc = 0; kc <= diagB; ++kc) {
        const bool actA = (kc <= diagA);
        const int key0 = kc * 64;

        // V for current step — issued early, consumed at step end
        const short* vb = Vbh + key0;
        bf16x8 vf[2][4];
        #pragma unroll
        for (int h = 0; h < 2; ++h)
            #pragma unroll
            for (int dt = 0; dt < 4; ++dt)
                vf[h][dt] = *(const bf16x8*)&vb[voff[dt] + h * 32];

        // ---- QK (S^T = K.Q^T): consumes kf ----
        f32x4 svA[4], svB[4];
        #pragma unroll
        for (int s = 0; s < 4; ++s) {
            f32x4 a = {0.f, 0.f, 0.f, 0.f};
            a = MFMA16(kf[s][0], qfB[0], a);
            a = MFMA16(kf[s][1], qfB[1], a);
            svB[s] = a;
            if (actA) {
                f32x4 b = {0.f, 0.f, 0.f, 0.f};
                b = MFMA16(kf[s][0], qfA[0], b);
                b = MFMA16(kf[s][1], qfA[1], b);
                svA[s] = b;
            }
        }

        // ---- prefetch next step's K into the same regs (off critical path) ----
        if (kc < diagB) {
            const short* kb = Kbh + (size_t)(key0 + 64) * 3072;
            #pragma unroll
            for (int s = 0; s < 4; ++s) {
                kf[s][0] = *(const bf16x8*)&kb[koff[s]];
                kf[s][1] = *(const bf16x8*)&kb[koff[s] + 32];
            }
        }

        // ---- softmax + P^T -> per-wave LDS ----
        if (kc == diagB) {
            const int qq = q0B + l16;
            #pragma unroll
            for (int s = 0; s < 4; ++s) {
                const int keyb = key0 + s * 16 + quad * 4;
                #pragma unroll
                for (int r = 0; r < 4; ++r)
                    svB[s][r] = (keyb + r <= qq) ? svB[s][r] : -1e30f;
            }
        }
        #pragma unroll
        for (int s = 0; s < 4; ++s) {
            #pragma unroll
            for (int r = 0; r < 4; ++r) svB[s][r] = exp2f(svB[s][r]);
            laccB += (svB[s][0] + svB[s][1]) + (svB[s][2] + svB[s][3]);
            *(unsigned*)&pwB[l16 * 72 + s * 16 + quad * 4]     = pk_bf16(svB[s][0], svB[s][1]);
            *(unsigned*)&pwB[l16 * 72 + s * 16 + quad * 4 + 2] = pk_bf16(svB[s][2], svB[s][3]);
        }
        if (actA) {
            if (kc == diagA) {
                const int qq = q0A + l16;
                #pragma unroll
                for (int s = 0; s < 4; ++s) {
                    const int keyb = key0 + s * 16 + quad * 4;
                    #pragma unroll
                    for (int r = 0; r < 4; ++r)
                        svA[s][r] = (keyb + r <= qq) ? svA[s][r] : -1e30f;
                }
            }
            #pragma unroll
            for (int s = 0; s < 4; ++s) {
                #pragma unroll
                for (int r = 0; r < 4; ++r) svA[s][r] = exp2f(svA[s][r]);
                laccA += (svA[s][0] + svA[s][1]) + (svA[s][2] + svA[s][3]);
                *(unsigned*)&pwA[l16 * 72 + s * 16 + quad * 4]     = pk_bf16(svA[s][0], svA[s][1]);
                *(unsigned*)&pwA[l16 * 72 + s * 16 + quad * 4 + 2] = pk_bf16(svA[s][2], svA[s][3]);
            }
        }

        // ---- PV (O^T += V^T.P^T); wave-internal DS is in-order, no fence ----
        {
            bf16x8 pfB0 = *(const bf16x8*)&pwB[l16 * 72 + quad * 8];
            bf16x8 pfB1 = *(const bf16x8*)&pwB[l16 * 72 + 32 + quad * 8];
            #pragma unroll
            for (int dt = 0; dt < 4; ++dt) {
                otB[dt] = MFMA16(vf[0][dt], pfB0, otB[dt]);
                otB[dt] = MFMA16(vf[1][dt], pfB1, otB[dt]);
            }
            if (actA) {
                bf16x8 pfA0 = *(const bf16x8*)&pwA[l16 * 72 + quad * 8];
                bf16x8 pfA1 = *(const bf16x8*)&pwA[l16 * 72 + 32 + quad * 8];
                #pragma unroll
                for (int dt = 0; dt < 4; ++dt) {
                    otA[dt] = MFMA16(vf[0][dt], pfA0, otA[dt]);
                    otA[dt] = MFMA16(vf[1][dt], pfA1, otA[dt]);
                }
            }
        }
    }

    // ---- l reduction (lanes sharing l16 across quads) + epilogue ----
    laccA += __shfl_xor(laccA, 16);
    laccA += __shfl_xor(laccA, 32);
    laccB += __shfl_xor(laccB, 16);
    laccB += __shfl_xor(laccB, 32);
    const float invA = 1.0f / laccA, invB = 1.0f / laccB;

    #pragma unroll
    for (int dt = 0; dt < 4; ++dt) {
        *(unsigned*)&pwA[l16 * 72 + dt * 16 + quad * 4]     = pk_bf16(otA[dt][0] * invA, otA[dt][1] * invA);
        *(unsigned*)&pwA[l16 * 72 + dt * 16 + quad * 4 + 2] = pk_bf16(otA[dt][2] * invA, otA[dt][3] * invA);
        *(unsigned*)&pwB[l16 * 72 + dt * 16 + quad * 4]     = pk_bf16(otB[dt][0] * invB, otB[dt][1] * invB);
        *(unsigned*)&pwB[l16 * 72 + dt * 16 + quad * 4 + 2] = pk_bf16(otB[dt][2] * invB, otB[dt][3] * invB);
    }
    {
        const int qr = lane >> 2, dc = (lane & 3) * 16;
        bf16x8 a0 = *(const bf16x8*)&pwA[qr * 72 + dc];
        bf16x8 a1 = *(const bf16x8*)&pwA[qr * 72 + dc + 8];
        short* dstA = &comb[(rowbase + q0A + qr) * 1024 + hcol + dc];
        *(bf16x8*)dstA = a0;
        *(bf16x8*)(dstA + 8) = a1;
        bf16x8 b0 = *(const bf16x8*)&pwB[qr * 72 + dc];
        bf16x8 b1 = *(const bf16x8*)&pwB[qr * 72 + dc + 8];
        short* dstB = &comb[(rowbase + q0B + qr) * 1024 + hcol + dc];
        *(bf16x8*)dstB = b0;
        *(bf16x8*)(dstB + 8) = b1;
    }
}

// ---------- launch ----------
extern "C" void kernel_launch(void* const* d_in, const int* in_sizes, int n_in,
                              void* d_out, int out_size, void* d_ws, size_t ws_size,
                              hipStream_t stream)
{
    const float* enc = (const float*)d_in[0];
    const float* Wa  = (const float*)d_in[1];
    const float* ba  = (const float*)d_in[2];
    const float* Wo  = (const float*)d_in[3];
    const float* bo  = (const float*)d_in[4];
    float* out = (float*)d_out;

    char* ws = (char*)d_ws;
    short* Abf  = (short*)ws;                            // 8 MB; reused as comb
    short* comb = Abf;
    short* WtO  = (short*)(ws + ((size_t)8 << 20));      // 2 MB
    short* bbA  = (short*)(ws + ((size_t)10 << 20));     // 6 KB
    short* bbO  = (short*)(ws + ((size_t)10 << 20) + 16384);
    short* WtA  = (short*)(ws + ((size_t)11 << 20));     // 6 MB (dead after gemm1)
    short* Vtw  = (short*)(ws + ((size_t)11 << 20));     // 8 MB (overlaps dead WtA)
    short* qkv  = (short*)(ws + ((size_t)19 << 20));     // 24 MB

    prep_kernel<<<3074, 256, 0, stream>>>(enc, Wa, ba, Wo, bo, Abf, WtA, bbA, WtO, bbO);
    gemm_bt<128, false, true><<<dim3(24, 32), 256, 0, stream>>>(
        Abf, WtA, bbA, qkv, 4096, 3072, 1024);
    vtrans_kernel<<<dim3(32, 32), 256, 0, stream>>>(qkv, Vtw);
    attn_kernel<<<dim3(32, 32), 128, 0, stream>>>(qkv, Vtw, comb);
    gemm_bt<64, true, false><<<dim3(16, 32), 256, 0, stream>>>(
        comb, WtO, bbO, out, 4096, 1024, 1024);
}

// Round 10
// 190.242 us; speedup vs baseline: 1.4229x; 1.2943x over previous
//
#include <hip/hip_runtime.h>
#include <hip/hip_bf16.h>

// ---------- types / helpers ----------
typedef __attribute__((ext_vector_type(8))) short bf16x8;   // 8 bf16 = 4 VGPRs
typedef __attribute__((ext_vector_type(4))) short bf16x4;
typedef __attribute__((ext_vector_type(4))) float f32x4;

__device__ __forceinline__ short f2bf(float f) {
    unsigned u = __float_as_uint(f);
    u += 0x7fff + ((u >> 16) & 1);          // round-to-nearest-even
    return (short)(u >> 16);
}
__device__ __forceinline__ float bf2f(short s) {
    return __uint_as_float(((unsigned)(unsigned short)s) << 16);
}
__device__ __forceinline__ unsigned pk_bf16(float lo, float hi) {
    __hip_bfloat162 t = __float22bfloat162_rn(make_float2(lo, hi));
    unsigned u;
    __builtin_memcpy(&u, &t, 4);
    return u;
}

#define GLOAD_LDS16(gp, lp)                                                            \
    __builtin_amdgcn_global_load_lds(                                                  \
        (const __attribute__((address_space(1))) unsigned*)(gp),                       \
        (__attribute__((address_space(3))) unsigned*)(lp), 16, 0, 0)

#define QK_SCALE 0.180336879f   // (1/sqrt(64)) * log2(e), folded into q at GEMM1
#define MFMA16(a, b, c) __builtin_amdgcn_mfma_f32_16x16x32_bf16((a), (b), (c), 0, 0, 0)

// ---------- fused prep: enc->bf16, biases->bf16, Wa/Wo -> transposed bf16 ----------
__device__ __forceinline__ void tcvt_tile(const float* __restrict__ W, short* __restrict__ Wt,
                                          int K, int N, int bx, int by, int t,
                                          short (*tile)[72]) {
    const int k0 = by * 64, n0 = bx * 64;
    #pragma unroll
    for (int jj = 0; jj < 4; ++jj) {
        int row = jj * 16 + (t >> 4);
        int col = (t & 15) * 4;
        f32x4 v = *(const f32x4*)&W[(size_t)(k0 + row) * N + n0 + col];
        bf16x4 b = {f2bf(v.x), f2bf(v.y), f2bf(v.z), f2bf(v.w)};
        *(bf16x4*)&tile[row][col] = b;
    }
    __syncthreads();
    const int nr = t >> 2, kc = (t & 3) * 16;
    bf16x8 o0, o1;
    #pragma unroll
    for (int j = 0; j < 8; ++j) { o0[j] = tile[kc + j][nr]; o1[j] = tile[kc + 8 + j][nr]; }
    short* dst = &Wt[(size_t)(n0 + nr) * K + k0 + kc];
    *(bf16x8*)dst = o0;
    *(bf16x8*)(dst + 8) = o1;
}

__global__ __launch_bounds__(256) void prep_kernel(
    const float* __restrict__ enc, const float* __restrict__ Wa,
    const float* __restrict__ ba, const float* __restrict__ Wo,
    const float* __restrict__ bo, short* __restrict__ Abf,
    short* __restrict__ WtA, short* __restrict__ bbA,
    short* __restrict__ WtO, short* __restrict__ bbO)
{
    __shared__ alignas(16) short tile[64][72];
    const int id = blockIdx.x, t = threadIdx.x;
    if (id < 2048) {
        const int i = id * 2048 + t * 8;
        f32x4 a = *(const f32x4*)&enc[i];
        f32x4 b = *(const f32x4*)&enc[i + 4];
        bf16x8 o = {f2bf(a.x), f2bf(a.y), f2bf(a.z), f2bf(a.w),
                    f2bf(b.x), f2bf(b.y), f2bf(b.z), f2bf(b.w)};
        *(bf16x8*)&Abf[i] = o;
    } else if (id == 2048) {
        for (int j = t * 8; j < 3072; j += 2048) {
            f32x4 a = *(const f32x4*)&ba[j];
            f32x4 b = *(const f32x4*)&ba[j + 4];
            bf16x8 o = {f2bf(a.x), f2bf(a.y), f2bf(a.z), f2bf(a.w),
                        f2bf(b.x), f2bf(b.y), f2bf(b.z), f2bf(b.w)};
            *(bf16x8*)&bbA[j] = o;
        }
    } else if (id == 2049) {
        if (t < 128) {
            const int j = t * 8;
            f32x4 a = *(const f32x4*)&bo[j];
            f32x4 b = *(const f32x4*)&bo[j + 4];
            bf16x8 o = {f2bf(a.x), f2bf(a.y), f2bf(a.z), f2bf(a.w),
                        f2bf(b.x), f2bf(b.y), f2bf(b.z), f2bf(b.w)};
            *(bf16x8*)&bbO[j] = o;
        }
        __syncthreads();
    } else if (id < 2818) {
        const int lid = id - 2050;
        tcvt_tile(Wa, WtA, 1024, 3072, lid % 48, lid / 48, t, tile);
    } else {
        const int lid = id - 2818;
        tcvt_tile(Wo, WtO, 1024, 1024, lid % 16, lid / 16, t, tile);
    }
}

// ---------- m97-style BT GEMM: C = A @ Bt^T + bias ----------
// SPLIT3: N=3072, col group g=n0>>10 routes to Q/K/V dense [4096][1024] slabs,
// q columns scaled by QK_SCALE. Else: single output (fp32 if F32OUT).
template<int BN, bool F32OUT, bool SPLIT3>
__global__ __launch_bounds__(256) void gemm_bt(
    const short* __restrict__ A, const short* __restrict__ Bt,
    const short* __restrict__ bias, void* __restrict__ C,
    short* __restrict__ Kw, short* __restrict__ Vw, int M, int N, int K)
{
    __shared__ alignas(16) short As[128 * 32];
    __shared__ alignas(16) short Bs[BN * 32];

    const int tid = threadIdx.x, w = tid >> 6, lane = tid & 63;
    const int quad = lane >> 4, l16 = lane & 15;
    constexpr int MT = (BN == 128) ? 4 : 2;
    const int wm = (BN == 128) ? (w >> 1) : w;
    const int wn = (BN == 128) ? (w & 1) : 0;
    const int m0 = blockIdx.y * 128, n0 = blockIdx.x * BN;
    const int srow = lane >> 2, scol = (lane & 3) * 8;

    f32x4 acc[MT][4] = {};

    for (int k0 = 0; k0 < K; k0 += 32) {
        __syncthreads();
        #pragma unroll
        for (int jj = 0; jj < 2; ++jj) {
            const int rb = w * 32 + jj * 16;
            GLOAD_LDS16(&A[(size_t)(m0 + rb + srow) * K + k0 + scol], &As[rb * 32]);
        }
        if (BN == 128) {
            #pragma unroll
            for (int jj = 0; jj < 2; ++jj) {
                const int rb = w * 32 + jj * 16;
                GLOAD_LDS16(&Bt[(size_t)(n0 + rb + srow) * K + k0 + scol], &Bs[rb * 32]);
            }
        } else {
            const int rb = w * 16;
            GLOAD_LDS16(&Bt[(size_t)(n0 + rb + srow) * K + k0 + scol], &Bs[rb * 32]);
        }
        __syncthreads();
        bf16x8 af[MT], bfr[4];
        #pragma unroll
        for (int i = 0; i < MT; ++i)
            af[i] = *(const bf16x8*)&As[(wm * (MT * 16) + i * 16 + l16) * 32 + quad * 8];
        #pragma unroll
        for (int i = 0; i < 4; ++i)
            bfr[i] = *(const bf16x8*)&Bs[(wn * 64 + i * 16 + l16) * 32 + quad * 8];
        #pragma unroll
        for (int mt = 0; mt < MT; ++mt)
            #pragma unroll
            for (int nt = 0; nt < 4; ++nt)
                acc[mt][nt] = MFMA16(af[mt], bfr[nt], acc[mt][nt]);
    }

    if (SPLIT3) {
        const int g = n0 >> 10;                     // 0=q,1=k,2=v (block-uniform)
        short* dstb = (g == 0) ? (short*)C : (g == 1) ? Kw : Vw;
        const int lc0 = n0 & 1023;
        #pragma unroll
        for (int nt = 0; nt < 4; ++nt) {
            const int col = n0 + wn * 64 + nt * 16 + l16;
            const int lc = lc0 + wn * 64 + nt * 16 + l16;
            const float bv = bf2f(bias[col]);
            #pragma unroll
            for (int mt = 0; mt < 4; ++mt) {
                const int row = m0 + wm * 64 + mt * 16 + quad * 4;
                #pragma unroll
                for (int r = 0; r < 4; ++r) {
                    float v = acc[mt][nt][r] + bv;
                    if (g == 0) v *= QK_SCALE;
                    dstb[(size_t)(row + r) * 1024 + lc] = f2bf(v);
                }
            }
        }
    } else {
        #pragma unroll
        for (int nt = 0; nt < 4; ++nt) {
            const int col = n0 + wn * 64 + nt * 16 + l16;
            const float bv = bf2f(bias[col]);
            #pragma unroll
            for (int mt = 0; mt < MT; ++mt) {
                const int row = m0 + wm * (MT * 16) + mt * 16 + quad * 4;
                #pragma unroll
                for (int r = 0; r < 4; ++r) {
                    float v = acc[mt][nt][r] + bv;
                    if (F32OUT) ((float*)C)[(size_t)(row + r) * N + col] = v;
                    else        ((short*)C)[(size_t)(row + r) * N + col] = f2bf(v);
                }
            }
        }
    }
}

// ---------- fragment-swizzle prep: Kw/Vw -> Kx/Vx in MFMA fragment order ----------
// Kx[bh][kc][c=((s*2+h)*64+lane)][j]  = K[kc*64+s*16+(lane&15)][h*32+(lane>>4)*8+j]
// Vx[bh][kc][c=((h*4+dt)*64+lane)][j] = V[kc*64+h*32+(lane>>4)*8+j][dt*16+(lane&15)]
// -> every fragment load in attn becomes one fully-coalesced 1KB b128 load.
__global__ __launch_bounds__(256) void fragprep_kernel(
    const short* __restrict__ Kw, const short* __restrict__ Vw,
    short* __restrict__ Kx, short* __restrict__ Vx)
{
    __shared__ alignas(16) short T[64][72];
    const int t = threadIdx.x;
    const int kc = blockIdx.x, bh = blockIdx.y;
    const int batch = bh >> 4, head = bh & 15;
    const size_t srcbase = ((size_t)batch * 2048 + kc * 64) * 1024 + head * 64;
    short* kxdst = Kx + ((size_t)bh * 32 + kc) * 4096;
    short* vxdst = Vx + ((size_t)bh * 32 + kc) * 4096;

    // Kx gather (divergent read once, coalesced write)
    #pragma unroll
    for (int i = 0; i < 2; ++i) {
        const int c = i * 256 + t;
        const int lane = c & 63, sh = c >> 6;
        const int s = sh >> 1, h = sh & 1;
        const int l16 = lane & 15, quad = lane >> 4;
        bf16x8 v = *(const bf16x8*)&Kw[srcbase + (size_t)(s * 16 + l16) * 1024 + h * 32 + quad * 8];
        *(bf16x8*)&kxdst[c * 8] = v;
    }
    // V tile -> LDS transposed [d][key]
    #pragma unroll
    for (int i = 0; i < 2; ++i) {
        const int c = i * 256 + t;
        const int row = c >> 3, d0 = (c & 7) * 8;
        bf16x8 v = *(const bf16x8*)&Vw[srcbase + (size_t)row * 1024 + d0];
        #pragma unroll
        for (int j = 0; j < 8; ++j) T[d0 + j][row] = v[j];
    }
    __syncthreads();
    // Vx chunks (b128 LDS read, coalesced write)
    #pragma unroll
    for (int i = 0; i < 2; ++i) {
        const int c = i * 256 + t;
        const int lane = c & 63, hd = c >> 6;
        const int h = hd >> 2, dt = hd & 3;
        const int l16 = lane & 15, quad = lane >> 4;
        bf16x8 v = *(const bf16x8*)&T[dt * 16 + l16][h * 32 + quad * 8];
        *(bf16x8*)&vxdst[c * 8] = v;
    }
}

// ---------- barrier-free causal flash attention, fragment-coalesced loads ----------
// Round-9 structure (paired {tA,63-tA} 32-row tiles, K prefetch, static-max
// softmax, S^T formulation). K/V now read from Kx/Vx in fragment order: each
// load = contiguous 1KB (16 cache lines vs 64) -> 4x fewer TA line-txns.
__global__ __launch_bounds__(128) void attn_kernel(
    const short* __restrict__ Qw, const short* __restrict__ Kx,
    const short* __restrict__ Vx, short* __restrict__ comb)
{
    __shared__ alignas(16) short Ps[2][2][16 * 72];   // [wave][tile A/B]

    const int tid = threadIdx.x, w = tid >> 6, lane = tid & 63;
    const int quad = lane >> 4, l16 = lane & 15;
    const int bh = blockIdx.x;
    const int tA = blockIdx.y, tB = 63 - tA;
    const int batch = bh >> 4, head = bh & 15;
    const size_t rowbase = (size_t)batch * 2048;
    const int hcol = head * 64;
    const int q0A = tA * 32 + w * 16, q0B = tB * 32 + w * 16;
    const int diagA = tA >> 1, diagB = tB >> 1;
    const short* Kxbh = Kx + (size_t)bh * 131072;
    const short* Vxbh = Vx + (size_t)bh * 131072;
    const int lofs = lane * 8;
    short* pwA = &Ps[w][0][0];
    short* pwB = &Ps[w][1][0];

    // Q fragments (B-operand: q = l16, d = quad*8+j (+32))
    bf16x8 qfA[2], qfB[2];
    {
        const short* pa = &Qw[(rowbase + q0A + l16) * 1024 + hcol];
        const short* pb = &Qw[(rowbase + q0B + l16) * 1024 + hcol];
        qfA[0] = *(const bf16x8*)(pa + quad * 8);
        qfA[1] = *(const bf16x8*)(pa + 32 + quad * 8);
        qfB[0] = *(const bf16x8*)(pb + quad * 8);
        qfB[1] = *(const bf16x8*)(pb + 32 + quad * 8);
    }

    f32x4 otA[4] = {}, otB[4] = {};
    float laccA = 0.f, laccB = 0.f;

    // preload K fragments for step 0 (coalesced chunks)
    bf16x8 kf[4][2];
    #pragma unroll
    for (int s = 0; s < 4; ++s) {
        kf[s][0] = *(const bf16x8*)&Kxbh[(s * 2 + 0) * 512 + lofs];
        kf[s][1] = *(const bf16x8*)&Kxbh[(s * 2 + 1) * 512 + lofs];
    }

    for (int kc = 0; kc <= diagB; ++kc) {
        const bool actA = (kc <= diagA);
        const int key0 = kc * 64;

        // V fragments for current step — issued early, consumed at step end
        const short* vb = Vxbh + kc * 4096;
        bf16x8 vf[2][4];
        #pragma unroll
        for (int h = 0; h < 2; ++h)
            #pragma unroll
            for (int dt = 0; dt < 4; ++dt)
                vf[h][dt] = *(const bf16x8*)&vb[(h * 4 + dt) * 512 + lofs];

        // ---- QK (S^T = K.Q^T): consumes kf ----
        f32x4 svA[4], svB[4];
        #pragma unroll
        for (int s = 0; s < 4; ++s) {
            f32x4 a = {0.f, 0.f, 0.f, 0.f};
            a = MFMA16(kf[s][0], qfB[0], a);
            a = MFMA16(kf[s][1], qfB[1], a);
            svB[s] = a;
            if (actA) {
                f32x4 b = {0.f, 0.f, 0.f, 0.f};
                b = MFMA16(kf[s][0], qfA[0], b);
                b = MFMA16(kf[s][1], qfA[1], b);
                svA[s] = b;
            }
        }

        // ---- prefetch next step's K (off critical path) ----
        if (kc < diagB) {
            const short* kb = Kxbh + (kc + 1) * 4096;
            #pragma unroll
            for (int s = 0; s < 4; ++s) {
                kf[s][0] = *(const bf16x8*)&kb[(s * 2 + 0) * 512 + lofs];
                kf[s][1] = *(const bf16x8*)&kb[(s * 2 + 1) * 512 + lofs];
            }
        }

        // ---- softmax + P^T -> per-wave LDS ----
        if (kc == diagB) {
            const int qq = q0B + l16;
            #pragma unroll
            for (int s = 0; s < 4; ++s) {
                const int keyb = key0 + s * 16 + quad * 4;
                #pragma unroll
                for (int r = 0; r < 4; ++r)
                    svB[s][r] = (keyb + r <= qq) ? svB[s][r] : -1e30f;
            }
        }
        #pragma unroll
        for (int s = 0; s < 4; ++s) {
            #pragma unroll
            for (int r = 0; r < 4; ++r) svB[s][r] = exp2f(svB[s][r]);
            laccB += (svB[s][0] + svB[s][1]) + (svB[s][2] + svB[s][3]);
            *(unsigned*)&pwB[l16 * 72 + s * 16 + quad * 4]     = pk_bf16(svB[s][0], svB[s][1]);
            *(unsigned*)&pwB[l16 * 72 + s * 16 + quad * 4 + 2] = pk_bf16(svB[s][2], svB[s][3]);
        }
        if (actA) {
            if (kc == diagA) {
                const int qq = q0A + l16;
                #pragma unroll
                for (int s = 0; s < 4; ++s) {
                    const int keyb = key0 + s * 16 + quad * 4;
                    #pragma unroll
                    for (int r = 0; r < 4; ++r)
                        svA[s][r] = (keyb + r <= qq) ? svA[s][r] : -1e30f;
                }
            }
            #pragma unroll
            for (int s = 0; s < 4; ++s) {
                #pragma unroll
                for (int r = 0; r < 4; ++r) svA[s][r] = exp2f(svA[s][r]);
                laccA += (svA[s][0] + svA[s][1]) + (svA[s][2] + svA[s][3]);
                *(unsigned*)&pwA[l16 * 72 + s * 16 + quad * 4]     = pk_bf16(svA[s][0], svA[s][1]);
                *(unsigned*)&pwA[l16 * 72 + s * 16 + quad * 4 + 2] = pk_bf16(svA[s][2], svA[s][3]);
            }
        }

        // ---- PV (O^T += V^T.P^T); wave-internal DS is in-order ----
        {
            bf16x8 pfB0 = *(const bf16x8*)&pwB[l16 * 72 + quad * 8];
            bf16x8 pfB1 = *(const bf16x8*)&pwB[l16 * 72 + 32 + quad * 8];
            #pragma unroll
            for (int dt = 0; dt < 4; ++dt) {
                otB[dt] = MFMA16(vf[0][dt], pfB0, otB[dt]);
                otB[dt] = MFMA16(vf[1][dt], pfB1, otB[dt]);
            }
            if (actA) {
                bf16x8 pfA0 = *(const bf16x8*)&pwA[l16 * 72 + quad * 8];
                bf16x8 pfA1 = *(const bf16x8*)&pwA[l16 * 72 + 32 + quad * 8];
                #pragma unroll
                for (int dt = 0; dt < 4; ++dt) {
                    otA[dt] = MFMA16(vf[0][dt], pfA0, otA[dt]);
                    otA[dt] = MFMA16(vf[1][dt], pfA1, otA[dt]);
                }
            }
        }
    }

    // ---- l reduction (lanes sharing l16 across quads) + epilogue ----
    laccA += __shfl_xor(laccA, 16);
    laccA += __shfl_xor(laccA, 32);
    laccB += __shfl_xor(laccB, 16);
    laccB += __shfl_xor(laccB, 32);
    const float invA = 1.0f / laccA, invB = 1.0f / laccB;

    #pragma unroll
    for (int dt = 0; dt < 4; ++dt) {
        *(unsigned*)&pwA[l16 * 72 + dt * 16 + quad * 4]     = pk_bf16(otA[dt][0] * invA, otA[dt][1] * invA);
        *(unsigned*)&pwA[l16 * 72 + dt * 16 + quad * 4 + 2] = pk_bf16(otA[dt][2] * invA, otA[dt][3] * invA);
        *(unsigned*)&pwB[l16 * 72 + dt * 16 + quad * 4]     = pk_bf16(otB[dt][0] * invB, otB[dt][1] * invB);
        *(unsigned*)&pwB[l16 * 72 + dt * 16 + quad * 4 + 2] = pk_bf16(otB[dt][2] * invB, otB[dt][3] * invB);
    }
    {
        const int qr = lane >> 2, dc = (lane & 3) * 16;
        bf16x8 a0 = *(const bf16x8*)&pwA[qr * 72 + dc];
        bf16x8 a1 = *(const bf16x8*)&pwA[qr * 72 + dc + 8];
        short* dstA = &comb[(rowbase + q0A + qr) * 1024 + hcol + dc];
        *(bf16x8*)dstA = a0;
        *(bf16x8*)(dstA + 8) = a1;
        bf16x8 b0 = *(const bf16x8*)&pwB[qr * 72 + dc];
        bf16x8 b1 = *(const bf16x8*)&pwB[qr * 72 + dc + 8];
        short* dstB = &comb[(rowbase + q0B + qr) * 1024 + hcol + dc];
        *(bf16x8*)dstB = b0;
        *(bf16x8*)(dstB + 8) = b1;
    }
}

// ---------- launch ----------
extern "C" void kernel_launch(void* const* d_in, const int* in_sizes, int n_in,
                              void* d_out, int out_size, void* d_ws, size_t ws_size,
                              hipStream_t stream)
{
    const float* enc = (const float*)d_in[0];
    const float* Wa  = (const float*)d_in[1];
    const float* ba  = (const float*)d_in[2];
    const float* Wo  = (const float*)d_in[3];
    const float* bo  = (const float*)d_in[4];
    float* out = (float*)d_out;

    // layout (43 MB peak, same as before):
    // [0,8)  Abf (dead after gemm1)  -> Kx
    // [8,10) WtO   [10,11) biases    [11,19) WtA(6, dead after gemm1) -> Vx
    // [19,27) Qw   [27,35) Kw (dead after fragprep) -> comb   [35,43) Vw
    char* ws = (char*)d_ws;
    short* Abf  = (short*)ws;
    short* Kx   = (short*)ws;
    short* WtO  = (short*)(ws + ((size_t)8 << 20));
    short* bbA  = (short*)(ws + ((size_t)10 << 20));
    short* bbO  = (short*)(ws + ((size_t)10 << 20) + 16384);
    short* WtA  = (short*)(ws + ((size_t)11 << 20));
    short* Vx   = (short*)(ws + ((size_t)11 << 20));
    short* Qw   = (short*)(ws + ((size_t)19 << 20));
    short* Kw   = (short*)(ws + ((size_t)27 << 20));
    short* comb = (short*)(ws + ((size_t)27 << 20));
    short* Vw   = (short*)(ws + ((size_t)35 << 20));

    prep_kernel<<<3074, 256, 0, stream>>>(enc, Wa, ba, Wo, bo, Abf, WtA, bbA, WtO, bbO);
    gemm_bt<128, false, true><<<dim3(24, 32), 256, 0, stream>>>(
        Abf, WtA, bbA, Qw, Kw, Vw, 4096, 3072, 1024);
    fragprep_kernel<<<dim3(32, 32), 256, 0, stream>>>(Kw, Vw, Kx, Vx);
    attn_kernel<<<dim3(32, 32), 128, 0, stream>>>(Qw, Kx, Vx, comb);
    gemm_bt<64, true, false><<<dim3(16, 32), 256, 0, stream>>>(
        comb, WtO, bbO, out, nullptr, nullptr, 4096, 1024, 1024);
}